// Round 17
// baseline (1082.155 us; speedup 1.0000x reference)
//
#include <hip/hip_runtime.h>
#include <hip/hip_bf16.h>

// ---------------------------------------------------------------------------
// B=4, L=1024, E=512, H=8, NL=2, M=2048, S=256, R=2, Dh=64
// Both transformer directions merged: residual stream HB has 8192 rows,
// row = d*4096 + b*1024 + i ; "bb" = row>>10 = d*4+b (8 merged batches).
// ---------------------------------------------------------------------------

#define NEGF -3.4028235e38f
#define LOG2E 1.4426950408889634f

using bf16x8 = __attribute__((ext_vector_type(8))) short;
using f32x4  = __attribute__((ext_vector_type(4))) float;

__device__ inline float bf2f(unsigned short u) {
    return __uint_as_float(((unsigned int)u) << 16);
}
__device__ inline unsigned short f2b(float f) {
    unsigned int u = __float_as_uint(f);
    return (unsigned short)((u + 0x7fff + ((u >> 16) & 1)) >> 16);
}

__device__ inline void gl_lds16(const void* g, void* l) {
    __builtin_amdgcn_global_load_lds(
        (const __attribute__((address_space(1))) void*)(uintptr_t)g,
        (__attribute__((address_space(3))) void*)(unsigned int)(uintptr_t)l,
        16, 0, 0);
}

// ---------------------------------------------------------------------------
// bf16 MFMA GEMM, BM in {64,128}, BN=128, BK=32, 4 waves. TWO LDS buffers,
// depth-1 prefetch, single top-of-iteration barrier -> 24 KB LDS (BM=64)
// -> up to 6 blocks/CU for TLP latency hiding. Counted vmcnt: 3 loads per
// thread per stage (BM=64; 4 for BM=128), steady-state wait leaves the
// next-tile loads in flight. XCD-chunked block swizzle (grid total % 8 == 0).
// qkv==1 (N=1536): cols 0-511 -> Cb (Q, x0.125), 512-1023 -> CbK (K),
// 1024-1535 -> Ct (V per-head transposed (BB,8,64,1024)).
// qkv==0: Cf f32, Cb bf16, Ct per-head transposed with row-stride ldkv.
// ---------------------------------------------------------------------------
template<int BM>
__global__ __launch_bounds__(256) void gemm_bf16_k(
    const unsigned short* __restrict__ A,
    const unsigned short* __restrict__ Wt0, const unsigned short* __restrict__ Wt1,
    const float* __restrict__ bias0, const float* __restrict__ bias1, int mhalf,
    const float* __restrict__ res,
    float* __restrict__ Cf, unsigned short* __restrict__ Cb,
    unsigned short* __restrict__ CbK, unsigned short* __restrict__ Ct, int ldkv,
    int M, int N, int K, float alpha, int gelu_flag, int qkv)
{
    constexpr int MF  = BM / 32;
    constexpr int NAC = BM * 4 / 256;
    __shared__ unsigned short As[2][BM * 32];
    __shared__ unsigned short Bs[2][4096];
    const int tid  = threadIdx.x;
    const int wid  = tid >> 6;
    const int lane = tid & 63;
    const int wy   = wid >> 1, wx = wid & 1;
    const int koff = lane >> 4, l16 = lane & 15;

    const int flat = blockIdx.y * gridDim.x + blockIdx.x;
    const int cpx  = (gridDim.x * gridDim.y) >> 3;
    const int swz  = (flat & 7) * cpx + (flat >> 3);
    const int m0 = (swz / gridDim.x) * BM, n0 = (swz % gridDim.x) * 128;

    const unsigned short* Wt = (m0 < mhalf) ? Wt0 : Wt1;
    const float* bias = (m0 < mhalf) ? bias0 : bias1;

    const unsigned short* aG[NAC];
    const unsigned short* bG[2];
    #pragma unroll
    for (int i = 0; i < NAC; ++i) {
        int c = tid + i * 256;
        int r = ((c >> 6) << 4) | (c & 15), kk = ((c >> 4) & 3) << 3;
        aG[i] = A + (size_t)(m0 + r) * K + kk;
    }
    #pragma unroll
    for (int i = 0; i < 2; ++i) {
        int c = tid + i * 256;
        int r = ((c >> 6) << 4) | (c & 15), kk = ((c >> 4) & 3) << 3;
        bG[i] = Wt + (size_t)(n0 + r) * K + kk;
    }

    f32x4 acc[MF][4] = {};
    const int nk = K >> 5;

    auto stage = [&](int buf, int k0) {
        #pragma unroll
        for (int i = 0; i < NAC; ++i)
            gl_lds16(aG[i] + k0, &As[buf][(size_t)(i * 256 + wid * 64) * 8]);
        #pragma unroll
        for (int i = 0; i < 2; ++i)
            gl_lds16(bG[i] + k0, &Bs[buf][(size_t)(i * 256 + wid * 64) * 8]);
    };

    stage(0, 0);
    int cur = 0;
    for (int it = 0; it < nk; ++it) {
        const int ahead = nk - 1 - it;
        if (ahead >= 1) stage(cur ^ 1, (it + 1) << 5);
        if constexpr (BM == 128) {
            if (ahead >= 1) asm volatile("s_waitcnt vmcnt(4)" ::: "memory");
            else            asm volatile("s_waitcnt vmcnt(0)" ::: "memory");
        } else {
            if (ahead >= 1) asm volatile("s_waitcnt vmcnt(3)" ::: "memory");
            else            asm volatile("s_waitcnt vmcnt(0)" ::: "memory");
        }
        __builtin_amdgcn_s_barrier();   // single rendezvous per K-step

        bf16x8 af[MF], bfr[4];
        const int foff = (koff * 16 + l16) * 8;
        #pragma unroll
        for (int i = 0; i < MF; ++i)
            af[i] = *(const bf16x8*)&As[cur][(size_t)((wy * MF + i) * 64) * 8 + foff];
        #pragma unroll
        for (int j = 0; j < 4; ++j)
            bfr[j] = *(const bf16x8*)&Bs[cur][(size_t)((wx * 4 + j) * 64) * 8 + foff];
        #pragma unroll
        for (int i = 0; i < MF; ++i)
            #pragma unroll
            for (int j = 0; j < 4; ++j)
                acc[i][j] = __builtin_amdgcn_mfma_f32_16x16x32_bf16(
                    af[i], bfr[j], acc[i][j], 0, 0, 0);

        cur ^= 1;
    }

    #pragma unroll
    for (int i = 0; i < MF; ++i) {
        const int rbase = m0 + wy * (MF * 16) + i * 16 + koff * 4;
        #pragma unroll
        for (int j = 0; j < 4; ++j) {
            const int gn = n0 + wx * 64 + j * 16 + l16;
            const float bs = bias ? bias[gn] : 0.f;
            if (qkv) {
                const int seg = gn >> 9, gnl = gn & 511;
                const float av = (seg == 0) ? 0.125f : 1.0f;
                unsigned short o[4];
                #pragma unroll
                for (int r = 0; r < 4; ++r) o[r] = f2b((acc[i][j][r] + bs) * av);
                if (seg == 0) {
                    #pragma unroll
                    for (int r = 0; r < 4; ++r)
                        Cb[(size_t)(rbase + r) * 512 + gnl] = o[r];
                } else if (seg == 1) {
                    #pragma unroll
                    for (int r = 0; r < 4; ++r)
                        CbK[(size_t)(rbase + r) * 512 + gnl] = o[r];
                } else {
                    const int hh = gnl >> 6, dh = gnl & 63;
                    const int bb = rbase >> 10, l0 = rbase & 1023;
                    *(ushort4*)(Ct + ((size_t)(bb * 8 + hh) * 64 + dh) * 1024 + l0) =
                        make_ushort4(o[0], o[1], o[2], o[3]);
                }
            } else {
                float vr[4];
                #pragma unroll
                for (int r = 0; r < 4; ++r) {
                    float v = (acc[i][j][r] + bs) * alpha;
                    if (gelu_flag) v = 0.5f * v * (1.0f + erff(v * 0.70710678118654752f));
                    const size_t idx = (size_t)(rbase + r) * N + gn;
                    if (res) v += res[idx];
                    if (Cf) Cf[idx] = v;
                    if (Cb) Cb[idx] = f2b(v);
                    vr[r] = v;
                }
                if (Ct) {
                    const int hh = gn >> 6, dh = gn & 63;
                    const int bb = rbase / ldkv;
                    const int l0 = rbase - bb * ldkv;
                    *(ushort4*)(Ct + ((size_t)(bb * 8 + hh) * 64 + dh) * ldkv + l0) =
                        make_ushort4(f2b(vr[0]), f2b(vr[1]), f2b(vr[2]), f2b(vr[3]));
                }
            }
        }
    }
}

// ---------------------------------------------------------------------------
// weight transpose-convert: src fp32 [K][N] -> dst bf16 [N][K]
// ---------------------------------------------------------------------------
__global__ __launch_bounds__(256) void wconv(
    const float* __restrict__ src, unsigned short* __restrict__ dst,
    int K, int N, long sstride, long dstride)
{
    __shared__ float t[64][65];
    const int n0 = blockIdx.x * 64, k0 = blockIdx.y * 64;
    const float* s = src + (size_t)blockIdx.z * sstride;
    unsigned short* d = dst + (size_t)blockIdx.z * dstride;
    const int tid = threadIdx.x;
    #pragma unroll
    for (int i = 0; i < 4; ++i) {
        int lin = i * 1024 + tid * 4;
        int r = lin >> 6, c = lin & 63;
        float4 v = *(const float4*)(s + (size_t)(k0 + r) * N + n0 + c);
        t[r][c] = v.x; t[r][c + 1] = v.y; t[r][c + 2] = v.z; t[r][c + 3] = v.w;
    }
    __syncthreads();
    #pragma unroll
    for (int i = 0; i < 8; ++i) {
        int lin = i * 512 + tid * 2;
        int rn = lin >> 6, ck = lin & 63;
        ushort2 o;
        o.x = f2b(t[ck][rn]); o.y = f2b(t[ck + 1][rn]);
        *(ushort2*)(d + (size_t)(n0 + rn) * K + k0 + ck) = o;
    }
}

// ---------------------------------------------------------------------------
// Skinny GEMM for M=4, split-K, deterministic
// ---------------------------------------------------------------------------
__global__ __launch_bounds__(256) void skinny_k(
    const float* __restrict__ A, const float* __restrict__ W,
    float* __restrict__ P, int N, int K)
{
    const int n = blockIdx.x * 256 + threadIdx.x;
    const int s = blockIdx.y;
    const int k0 = s * 32;
    float a0 = 0.f, a1 = 0.f, a2 = 0.f, a3 = 0.f;
    #pragma unroll 8
    for (int k = k0; k < k0 + 32; ++k) {
        float w = W[(size_t)k * N + n];
        a0 = fmaf(A[k], w, a0);
        a1 = fmaf(A[K + k], w, a1);
        a2 = fmaf(A[2 * K + k], w, a2);
        a3 = fmaf(A[3 * K + k], w, a3);
    }
    float* p = P + (size_t)s * 4 * N;
    p[n] = a0; p[N + n] = a1; p[2 * N + n] = a2; p[3 * N + n] = a3;
}

__global__ __launch_bounds__(256) void skinny_red(
    const float* __restrict__ P, const float* __restrict__ bias,
    float* __restrict__ C, int N, int nsplit, int gelu_flag)
{
    const int n = blockIdx.x * 256 + threadIdx.x;
    const int r = blockIdx.y;
    float acc = 0.f;
    for (int s = 0; s < nsplit; ++s) acc += P[((size_t)s * 4 + r) * N + n];
    float v = acc + (bias ? bias[n] : 0.f);
    if (gelu_flag) v = 0.5f * v * (1.0f + erff(v * 0.70710678118654752f));
    C[(size_t)r * N + n] = v;
}

// ---------------------------------------------------------------------------
// LayerNorm; per-4096-row param offset pstride (merged directions), optional
// add + FiLM; fp32 in, fp32 and/or bf16 out.
// ---------------------------------------------------------------------------
__global__ __launch_bounds__(256) void ln_kernel(
    const float* __restrict__ X, const float* __restrict__ X2,
    const float* __restrict__ s, const float* __restrict__ b,
    float* __restrict__ Yf, unsigned short* __restrict__ Yb,
    int D, const float* __restrict__ film, int rows_per_batch, long pstride)
{
    const int row = blockIdx.x;
    const int tid = threadIdx.x;
    const float* x = X + (size_t)row * D;
    const float* x2 = X2 ? X2 + (size_t)row * D : nullptr;
    const float* se = s + (size_t)(row >> 12) * pstride;
    const float* be = b + (size_t)(row >> 12) * pstride;

    float sum = 0.f, sq = 0.f;
    for (int c = tid; c < D; c += 256) {
        float v = x[c] + (x2 ? x2[c] : 0.f);
        sum += v; sq += v * v;
    }
    __shared__ float r1[4], r2[4];
    __shared__ float s_mean, s_rstd;
    for (int off = 32; off > 0; off >>= 1) {
        sum += __shfl_down(sum, off);
        sq  += __shfl_down(sq,  off);
    }
    if ((tid & 63) == 0) { r1[tid >> 6] = sum; r2[tid >> 6] = sq; }
    __syncthreads();
    if (tid == 0) {
        float ts = r1[0] + r1[1] + r1[2] + r1[3];
        float tq = r2[0] + r2[1] + r2[2] + r2[3];
        float mean = ts / (float)D;
        float var = tq / (float)D - mean * mean;
        s_mean = mean;
        s_rstd = rsqrtf(var + 1e-5f);
    }
    __syncthreads();
    const float mean = s_mean, rstd = s_rstd;
    const float* fa = nullptr; const float* fb = nullptr;
    if (film) {
        int batch = row / rows_per_batch;
        fa = film + (size_t)batch * 2 * D;
        fb = fa + D;
    }
    for (int c = tid; c < D; c += 256) {
        float v = x[c] + (x2 ? x2[c] : 0.f);
        float y = (v - mean) * rstd * se[c] + be[c];
        if (film) y = fa[c] * y + fb[c];
        if (Yf) Yf[(size_t)row * D + c] = y;
        if (Yb) Yb[(size_t)row * D + c] = f2b(y);
    }
}

__global__ void temb_kernel(const float* __restrict__ t, float* __restrict__ temb,
                            unsigned short* __restrict__ tembb)
{
    int b = blockIdx.x;
    int i = threadIdx.x;
    float f = expf((float)i * (-9.210340371976184f / 255.0f));
    float a = t[b] * f;
    float sv = sinf(a), cv = cosf(a);
    temb[b * 512 + i]        = sv;
    temb[b * 512 + 256 + i]  = cv;
    tembb[b * 512 + i]       = f2b(sv);
    tembb[b * 512 + 256 + i] = f2b(cv);
}

__global__ void embed_kernel(const int* __restrict__ x, const float* __restrict__ temb,
                             const float* __restrict__ embed,
                             float* __restrict__ l2r, float* __restrict__ r2l)
{
    const int i = blockIdx.x;
    const int b = blockIdx.y;
    const int d = blockIdx.z;
    float* out = (d == 0 ? l2r : r2l) + ((size_t)(b * 1024 + i) * 512);
    const float* src;
    if (d == 0) src = (i == 0)    ? temb + b * 512 : embed + (size_t)x[b * 1024 + (i - 1)] * 512;
    else        src = (i == 1023) ? temb + b * 512 : embed + (size_t)x[b * 1024 + (i + 1)] * 512;
    for (int e = threadIdx.x; e < 512; e += 256) {
        int j = e >> 1;
        float div = expf((float)(2 * j) * (-9.210340371976184f / 512.0f));
        float ang = (float)i * div;
        float pe = (e & 1) ? cosf(ang) : sinf(ang);
        out[e] = src[e] + pe;
    }
}

__global__ void add_kernel(const float* __restrict__ A, const float* __restrict__ B,
                           float* __restrict__ C, int n)
{
    int i = blockIdx.x * blockDim.x + threadIdx.x;
    int stride = gridDim.x * blockDim.x;
    for (; i < n; i += stride) C[i] = A[i] + B[i];
}

__global__ void add_bf16(const unsigned int* __restrict__ A,
                         const unsigned int* __restrict__ B,
                         unsigned int* __restrict__ C, int nwords)
{
    int i = blockIdx.x * blockDim.x + threadIdx.x;
    int stride = gridDim.x * blockDim.x;
    for (; i < nwords; i += stride) {
        unsigned int a = A[i], b = B[i];
        float lo = __uint_as_float(a << 16) + __uint_as_float(b << 16);
        float hi = __uint_as_float(a & 0xffff0000u) + __uint_as_float(b & 0xffff0000u);
        C[i] = (unsigned int)f2b(lo) | ((unsigned int)f2b(hi) << 16);
    }
}

__global__ void build_allv_b(const unsigned short* __restrict__ tembb,
                             const unsigned short* __restrict__ l2rn,
                             const unsigned short* __restrict__ r2ln,
                             unsigned short* __restrict__ allv)
{
    const int k = blockIdx.x;
    const int b = blockIdx.y;
    unsigned short* out = allv + ((size_t)b * 2080 + k) * 512;
    const unsigned short* src;
    if (k == 0)         src = tembb + b * 512;
    else if (k <= 1024) src = l2rn + ((size_t)(b * 1024 + (k - 1)) * 512);
    else                src = r2ln + ((size_t)(b * 1024 + (k - 1025)) * 512);
    ((uint4*)out)[threadIdx.x] = ((const uint4*)src)[threadIdx.x];
}

// ---------------------------------------------------------------------------
// MFMA flash attention (R15 best variant: KVBLK=64), bf16 in/out, fp32
// accumulate, T14 async staging with named uint4 registers. Equal-work
// pairing for merged self-attention: one block processes the complementary
// q-tile pair (qt, 15-qt) sequentially -> exactly 17 tiles per block.
// mode -1 (merged self): grid 512; qp=w&7, h=(w>>3)&7, bb=w>>6, dir=bb>>2.
// mode  2 (cross):       grid 512; qt=w&15, h=(w>>4)&7, bb=w>>7.
// ---------------------------------------------------------------------------
__global__ __launch_bounds__(256) void attn_mfma(
    const unsigned short* __restrict__ Q, const unsigned short* __restrict__ K,
    const unsigned short* __restrict__ Vt, unsigned short* __restrict__ O, int mode)
{
    const int E = 512;
    const int LKP = (mode == 2) ? 2080 : 1024;
    const int idf = blockIdx.x;
    const int chunk = gridDim.x >> 3;
    const int w = (idf & 7) * chunk + (idf >> 3);
    int h, bb, dir, qn, qtA;
    if (mode == 2) { qn = 1; qtA = w & 15; h = (w >> 4) & 7; bb = w >> 7; dir = 2; }
    else           { qn = 2; qtA = w & 7;  h = (w >> 3) & 7; bb = w >> 6; dir = bb >> 2; }
    const int tid = threadIdx.x;
    const int wid = tid >> 6, lane = tid & 63;
    const int fr = lane & 15;
    const int fs = lane >> 4;

    __shared__ unsigned short Qs[4096];
    __shared__ unsigned short Ks[4096];
    __shared__ unsigned short Vs[4096];
    __shared__ unsigned short Ps[4][16][72];

    const unsigned short* Kb0 = K + ((size_t)bb * LKP) * E + h * 64;
    const unsigned short* Vb0 = Vt + (size_t)(bb * 8 + h) * 64 * LKP;
    const int sr = tid & 63, sc = tid >> 6;

    uint4 kr0, kr1, vr0, vr1;
#define LOAD_TILE(KT) do {                                                     \
        const unsigned short* Kbase_ = Kb0 + (size_t)((KT) * 64) * E;          \
        const unsigned short* Vbase_ = Vb0 + (KT) * 64;                        \
        kr0 = *(const uint4*)(Kbase_ + (size_t)sr * E + sc * 8);               \
        kr1 = *(const uint4*)(Kbase_ + (size_t)sr * E + (sc + 4) * 8);         \
        vr0 = *(const uint4*)(Vbase_ + (size_t)sr * LKP + sc * 8);             \
        vr1 = *(const uint4*)(Vbase_ + (size_t)sr * LKP + (sc + 4) * 8);       \
    } while (0)

    for (int p = 0; p < qn; ++p) {
        const int qt = (p == 0) ? qtA : (15 - qtA);
        const int q0 = qt * 64;
        const int wq0 = q0 + wid * 16;

        // stage Q tile for this pass
        {
            const unsigned short* Qbase = Q + ((size_t)bb * 1024 + q0) * E + h * 64;
            #pragma unroll
            for (int it = 0; it < 2; ++it) {
                int i = tid + it * 256;
                int r = i & 63, c = i >> 6;
                *(uint4*)&Qs[(size_t)(c * 64 + r) * 8] =
                    *(const uint4*)(Qbase + (size_t)r * E + c * 8);
            }
        }
        __syncthreads();
        const bf16x8 aq0 = *(const bf16x8*)&Qs[(size_t)(fs * 64 + wid * 16 + fr) * 8];
        const bf16x8 aq1 = *(const bf16x8*)&Qs[(size_t)((fs + 4) * 64 + wid * 16 + fr) * 8];

        float m_r[4], l_r[4];
        f32x4 o_acc[4] = {};
        #pragma unroll
        for (int r = 0; r < 4; ++r) { m_r[r] = NEGF; l_r[r] = 0.f; }

        // contiguous tile list for this qt
        int nt, ktA = 1;
        if (dir == 0)      nt = qt + 1;
        else if (dir == 1) nt = 16 - qt;
        else { ktA = (qt >= 1) ? qt : 1; nt = 1 + (qt + 16 - ktA + 1); }
        auto kt_of = [&](int j) -> int {
            if (dir == 0) return j;
            if (dir == 1) return qt + j;
            return (j == 0) ? 0 : (ktA + j - 1);
        };

        LOAD_TILE(kt_of(0));

        for (int j = 0; j < nt; ++j) {
            const int kt = kt_of(j);
            const int k0 = kt * 64;

            // all waves done reading previous K/V tile (and previous pass)
            asm volatile("s_waitcnt lgkmcnt(0)" ::: "memory");
            __builtin_amdgcn_s_barrier();

            *(uint4*)&Ks[(size_t)(sc * 64 + sr) * 8]       = kr0;
            *(uint4*)&Ks[(size_t)((sc + 4) * 64 + sr) * 8] = kr1;
            *(uint4*)&Vs[(size_t)(sc * 64 + sr) * 8]       = vr0;
            *(uint4*)&Vs[(size_t)((sc + 4) * 64 + sr) * 8] = vr1;
            if (j + 1 < nt) LOAD_TILE(kt_of(j + 1));
            else if (p + 1 < qn) {
                // prefetch first tile of the complementary q-tile
                const int qt2 = 15 - qtA;
                const int kt2 = (dir == 0) ? 0 : ((dir == 1) ? qt2 : 0);
                LOAD_TILE(kt2);
            }

            asm volatile("s_waitcnt lgkmcnt(0)" ::: "memory");
            __builtin_amdgcn_s_barrier();

            f32x4 s[4] = {};
            __builtin_amdgcn_s_setprio(1);
            #pragma unroll
            for (int t = 0; t < 4; ++t) {
                bf16x8 bk0 = *(const bf16x8*)&Ks[(size_t)(fs * 64 + t * 16 + fr) * 8];
                bf16x8 bk1 = *(const bf16x8*)&Ks[(size_t)((fs + 4) * 64 + t * 16 + fr) * 8];
                s[t] = __builtin_amdgcn_mfma_f32_16x16x32_bf16(aq0, bk0, s[t], 0, 0, 0);
                s[t] = __builtin_amdgcn_mfma_f32_16x16x32_bf16(aq1, bk1, s[t], 0, 0, 0);
            }
            __builtin_amdgcn_s_setprio(0);

            bool need_mask;
            if (dir != 2) need_mask = (kt == qt);
            else if (kt >= 1 && kt <= 15) need_mask = !((64 * kt - 1) > (q0 + 63));
            else if (kt >= 17)            need_mask = !((64 * kt + 63 - 1025) < q0);
            else                          need_mask = true;
            if (need_mask) {
                #pragma unroll
                for (int t = 0; t < 4; ++t) {
                    #pragma unroll
                    for (int r = 0; r < 4; ++r) {
                        int q = wq0 + fs * 4 + r;
                        int k = k0 + t * 16 + fr;
                        bool valid;
                        if (dir == 0)      valid = (k <= q);
                        else if (dir == 1) valid = (k >= q);
                        else valid = (k == 0) || (k <= 1024 ? (k - 1) > q : (k - 1025) < q);
                        if (!valid) s[t][r] = NEGF;
                    }
                }
            }

            float c_[4], rs[4];
            #pragma unroll
            for (int r = 0; r < 4; ++r) {
                float v = fmaxf(fmaxf(s[0][r], s[1][r]), fmaxf(s[2][r], s[3][r]));
                v = fmaxf(v, __shfl_xor(v, 1));
                v = fmaxf(v, __shfl_xor(v, 2));
                v = fmaxf(v, __shfl_xor(v, 4));
                v = fmaxf(v, __shfl_xor(v, 8));
                float mnew = fmaxf(m_r[r], v);
                c_[r] = exp2f((m_r[r] - mnew) * LOG2E);
                m_r[r] = mnew;
                rs[r] = 0.f;
            }
            #pragma unroll
            for (int t = 0; t < 4; ++t) {
                #pragma unroll
                for (int r = 0; r < 4; ++r) {
                    float pv = exp2f((s[t][r] - m_r[r]) * LOG2E);
                    s[t][r] = pv;
                    rs[r] += pv;
                }
            }
            #pragma unroll
            for (int r = 0; r < 4; ++r) {
                float v = rs[r];
                v += __shfl_xor(v, 1);
                v += __shfl_xor(v, 2);
                v += __shfl_xor(v, 4);
                v += __shfl_xor(v, 8);
                l_r[r] = l_r[r] * c_[r] + v;
                o_acc[0][r] *= c_[r]; o_acc[1][r] *= c_[r];
                o_acc[2][r] *= c_[r]; o_acc[3][r] *= c_[r];
            }

            // P -> bf16 via wave-private LDS (in-wave ordering; no barrier)
            #pragma unroll
            for (int t = 0; t < 4; ++t)
                #pragma unroll
                for (int r = 0; r < 4; ++r)
                    Ps[wid][fs * 4 + r][t * 16 + fr] = f2b(s[t][r]);

            bf16x8 pa0 = *(const bf16x8*)&Ps[wid][fr][fs * 8];
            bf16x8 pa1 = *(const bf16x8*)&Ps[wid][fr][fs * 8 + 32];
            __builtin_amdgcn_s_setprio(1);
            #pragma unroll
            for (int t = 0; t < 4; ++t) {
                bf16x8 bv0 = *(const bf16x8*)&Vs[(size_t)(fs * 64 + t * 16 + fr) * 8];
                bf16x8 bv1 = *(const bf16x8*)&Vs[(size_t)((fs + 4) * 64 + t * 16 + fr) * 8];
                o_acc[t] = __builtin_amdgcn_mfma_f32_16x16x32_bf16(pa0, bv0, o_acc[t], 0, 0, 0);
                o_acc[t] = __builtin_amdgcn_mfma_f32_16x16x32_bf16(pa1, bv1, o_acc[t], 0, 0, 0);
            }
            __builtin_amdgcn_s_setprio(0);
        }

        // epilogue for this q-tile
        unsigned short* Obase = O + ((size_t)bb * 1024 + q0) * E + h * 64;
        float invl[4];
        #pragma unroll
        for (int r = 0; r < 4; ++r) invl[r] = 1.f / l_r[r];
        #pragma unroll
        for (int t = 0; t < 4; ++t)
            #pragma unroll
            for (int r = 0; r < 4; ++r)
                Obase[(size_t)(wid * 16 + fs * 4 + r) * E + t * 16 + fr] =
                    f2b(o_acc[t][r] * invl[r]);

        if (p + 1 < qn) __syncthreads();   // Qs restage hazard between passes
    }
#undef LOAD_TILE
}

// ---------------------------------------------------------------------------

static inline void gemmb(hipStream_t st, int BM, const unsigned short* A,
                         const unsigned short* Wt0, const unsigned short* Wt1,
                         const float* bias0, const float* bias1, int mhalf,
                         const float* res, float* Cf, unsigned short* Cb,
                         unsigned short* CbK, unsigned short* Ct, int ldkv,
                         int M, int N, int K, float alpha, int gelu, int qkv)
{
    dim3 g(N / 128, M / BM);
    if (BM == 128)
        gemm_bf16_k<128><<<g, dim3(256), 0, st>>>(A, Wt0, Wt1, bias0, bias1, mhalf,
            res, Cf, Cb, CbK, Ct, ldkv, M, N, K, alpha, gelu, qkv);
    else
        gemm_bf16_k<64><<<g, dim3(256), 0, st>>>(A, Wt0, Wt1, bias0, bias1, mhalf,
            res, Cf, Cb, CbK, Ct, ldkv, M, N, K, alpha, gelu, qkv);
}

static inline void sgemm4(hipStream_t st, const float* A, const float* W,
                          const float* bias, float* C, float* P,
                          int N, int K, int gelu)
{
    const int nsplit = K / 32;
    skinny_k<<<dim3(N / 256, nsplit), 256, 0, st>>>(A, W, P, N, K);
    skinny_red<<<dim3(N / 256, 4), 256, 0, st>>>(P, bias, C, N, nsplit, gelu);
}

extern "C" void kernel_launch(void* const* d_in, const int* in_sizes, int n_in,
                              void* d_out, int out_size, void* d_ws, size_t ws_size,
                              hipStream_t stream)
{
    const int*   x      = (const int*)  d_in[0];
    const float* t      = (const float*)d_in[1];
    const float* embedW = (const float*)d_in[2];
    const float* attn_W = (const float*)d_in[3];
    const float* attn_b = (const float*)d_in[4];
    const float* ln_s   = (const float*)d_in[5];
    const float* ln_b   = (const float*)d_in[6];
    const float* mlp_W1 = (const float*)d_in[7];
    const float* mlp_b1 = (const float*)d_in[8];
    const float* mlp_W2 = (const float*)d_in[9];
    const float* mlp_b2 = (const float*)d_in[10];
    const float* ca_Wq  = (const float*)d_in[11];
    const float* ca_Wk  = (const float*)d_in[12];
    const float* ca_bk  = (const float*)d_in[13];
    const float* ca_Wv  = (const float*)d_in[14];
    const float* ca_bv  = (const float*)d_in[15];
    const float* ca_Wo  = (const float*)d_in[16];
    const float* ca_bo  = (const float*)d_in[17];
    const float* ro1s   = (const float*)d_in[18];
    const float* ro1b   = (const float*)d_in[19];
    const float* ro2s   = (const float*)d_in[20];
    const float* ro2b   = (const float*)d_in[21];
    const float* in_W   = (const float*)d_in[22];
    const float* in_b   = (const float*)d_in[23];
    const float* tm_W1  = (const float*)d_in[24];
    const float* tm_b1  = (const float*)d_in[25];
    const float* tm_W2  = (const float*)d_in[26];
    const float* tm_b2  = (const float*)d_in[27];
    const float* res_W1 = (const float*)d_in[28];
    const float* res_b1 = (const float*)d_in[29];
    const float* res_W2 = (const float*)d_in[30];
    const float* res_b2 = (const float*)d_in[31];
    const float* rls    = (const float*)d_in[32];
    const float* rlb    = (const float*)d_in[33];
    const float* film_W = (const float*)d_in[34];
    const float* film_b = (const float*)d_in[35];
    const float* out_W  = (const float*)d_in[36];
    const float* out_b  = (const float*)d_in[37];
    float* out = (float*)d_out;
    (void)ws_size; (void)in_sizes; (void)n_in; (void)out_size;

    char* base = (char*)d_ws;
    size_t off = 0;
    auto alloc = [&](size_t bytes) -> char* {
        char* p = base + off;
        off = (off + bytes + 255) & ~(size_t)255;
        return p;
    };
    float* TEMB  = (float*)alloc(8192);
    float* TM1   = (float*)alloc(32768);
    float* T4    = (float*)alloc(32768);
    float* FILM  = (float*)alloc(32768);
    unsigned short* TEMBb = (unsigned short*)alloc(4096);
    float* SKP   = (float*)alloc(2097152);

    float* HB  = (float*)alloc(16777216);        // merged residual stream (8192x512)
    float* L2R = HB;
    float* R2L = HB + 4096 * 512;
    float* Z   = (float*)alloc(8388608);
    float* H2  = (float*)alloc(16777216);
    float* Z2  = (float*)alloc(16777216);

    unsigned short* Zb  = (unsigned short*)alloc(8388608);   // 8192x512
    unsigned short* Qb  = (unsigned short*)alloc(8388608);
    unsigned short* Kb  = (unsigned short*)alloc(8388608);
    unsigned short* Vb  = (unsigned short*)alloc(8388608);   // V^T (8,8,64,1024)
    unsigned short* Ob  = (unsigned short*)alloc(8388608);
    unsigned short* H2b = (unsigned short*)alloc(8388608);

    unsigned short* BIG = (unsigned short*)alloc(33554432);
    unsigned short* MIDb  = BIG;                 // 8192x2048 bf16 (32 MB)
    unsigned short* ALLVb = BIG;                 // 8320x512 (readout)
    unsigned short* K2b   = BIG + 4259840;
    unsigned short* V2T   = BIG + 8519680;       // (4,8,64,2080)

    unsigned short* WT = (unsigned short*)alloc(45613056);
    const size_t wt_attn = 0,        wt_mlp1 = 4194304, wt_mlp2 = 8388608;
    const size_t wt_caq = 12582912,  wt_cak = 12845056, wt_cav = 13107200,
                 wt_cao = 13369344,  wt_in  = 13631488;
    const size_t wt_res1 = 14155776, wt_res2 = 18350080, wt_out = 22544384;

    wconv<<<dim3(8, 8, 16), 256, 0, stream>>>(attn_W, WT + wt_attn, 512, 512, 262144, 262144);
    wconv<<<dim3(32, 8, 4), 256, 0, stream>>>(mlp_W1, WT + wt_mlp1, 512, 2048, 1048576, 1048576);
    wconv<<<dim3(8, 32, 4), 256, 0, stream>>>(mlp_W2, WT + wt_mlp2, 2048, 512, 1048576, 1048576);
    wconv<<<dim3(8, 8), 256, 0, stream>>>(ca_Wq, WT + wt_caq, 512, 512, 0, 0);
    wconv<<<dim3(8, 8), 256, 0, stream>>>(ca_Wk, WT + wt_cak, 512, 512, 0, 0);
    wconv<<<dim3(8, 8), 256, 0, stream>>>(ca_Wv, WT + wt_cav, 512, 512, 0, 0);
    wconv<<<dim3(8, 8), 256, 0, stream>>>(ca_Wo, WT + wt_cao, 512, 512, 0, 0);
    wconv<<<dim3(16, 8), 256, 0, stream>>>(in_W, WT + wt_in, 512, 1024, 0, 0);
    wconv<<<dim3(32, 16, 2), 256, 0, stream>>>(res_W1, WT + wt_res1, 1024, 2048, 2097152, 2097152);
    wconv<<<dim3(16, 32, 2), 256, 0, stream>>>(res_W2, WT + wt_res2, 2048, 1024, 2097152, 2097152);
    wconv<<<dim3(4, 16), 256, 0, stream>>>(out_W, WT + wt_out, 1024, 256, 0, 0);

    temb_kernel<<<dim3(4), dim3(256), 0, stream>>>(t, TEMB, TEMBb);
    embed_kernel<<<dim3(1024, 4, 2), dim3(256), 0, stream>>>(x, TEMB, embedW, L2R, R2L);

    // ---- transformer blocks, both directions merged (M=8192) ----
    for (int l = 0; l < 2; ++l) {
        const size_t d1 = 2 + l;   // dl for d=1
        ln_kernel<<<8192, 256, 0, stream>>>(HB, nullptr,
            ln_s + (l * 2 + 0) * 512, ln_b + (l * 2 + 0) * 512,
            nullptr, Zb, 512, nullptr, 1024, 2048);
        gemmb(stream, 64, Zb,
              WT + wt_attn + (size_t)l * 1048576, WT + wt_attn + d1 * 1048576,
              attn_b + l * 2048, attn_b + d1 * 2048, 4096,
              nullptr, nullptr, Qb, Kb, Vb, 1024, 8192, 1536, 512, 1.f, 0, 1);
        attn_mfma<<<dim3(512), dim3(256), 0, stream>>>(Qb, Kb, Vb, Ob, -1);
        gemmb(stream, 64, Ob,
              WT + wt_attn + (size_t)(l * 4 + 3) * 262144,
              WT + wt_attn + (d1 * 4 + 3) * 262144,
              attn_b + (l * 4 + 3) * 512, attn_b + (d1 * 4 + 3) * 512, 4096,
              HB, HB, nullptr, nullptr, nullptr, 1, 8192, 512, 512, 1.f, 0, 0);
        ln_kernel<<<8192, 256, 0, stream>>>(HB, nullptr,
            ln_s + (l * 2 + 1) * 512, ln_b + (l * 2 + 1) * 512,
            nullptr, Zb, 512, nullptr, 1024, 2048);
        gemmb(stream, 64, Zb,
              WT + wt_mlp1 + (size_t)l * 1048576, WT + wt_mlp1 + d1 * 1048576,
              mlp_b1 + l * 2048, mlp_b1 + d1 * 2048, 4096,
              nullptr, nullptr, MIDb, nullptr, nullptr, 1, 8192, 2048, 512, 1.f, 1, 0);
        gemmb(stream, 64, MIDb,
              WT + wt_mlp2 + (size_t)l * 1048576, WT + wt_mlp2 + d1 * 1048576,
              mlp_b2 + l * 512, mlp_b2 + d1 * 512, 4096,
              HB, HB, nullptr, nullptr, nullptr, 1, 8192, 512, 2048, 1.f, 0, 0);
    }

    // ---- readout / cross-attention (M=4096) ----
    add_kernel<<<2048, 256, 0, stream>>>(L2R, R2L, Z, 2097152);
    ln_kernel<<<4096, 256, 0, stream>>>(L2R, nullptr, ro1s, ro1b, nullptr, Qb, 512, nullptr, 1024, 0);
    ln_kernel<<<4096, 256, 0, stream>>>(R2L, nullptr, ro2s, ro2b, nullptr, Kb, 512, nullptr, 1024, 0);
    add_bf16<<<1024, 256, 0, stream>>>((const unsigned int*)Qb, (const unsigned int*)Kb,
                                       (unsigned int*)Vb, 1048576);
    build_allv_b<<<dim3(2049, 4), 64, 0, stream>>>(TEMBb, Qb, Kb, ALLVb);
    gemmb(stream, 64, Vb, WT + wt_caq, WT + wt_caq, nullptr, nullptr, 1 << 30,
          nullptr, nullptr, Zb, nullptr, nullptr, 1, 4096, 512, 512, 0.125f, 0, 0);
    gemmb(stream, 64, ALLVb, WT + wt_cak, WT + wt_cak, ca_bk, ca_bk, 1 << 30,
          nullptr, nullptr, K2b, nullptr, nullptr, 1, 8320, 512, 512, 1.f, 0, 0);
    gemmb(stream, 64, ALLVb, WT + wt_cav, WT + wt_cav, ca_bv, ca_bv, 1 << 30,
          nullptr, nullptr, nullptr, nullptr, V2T, 2080, 8320, 512, 512, 1.f, 0, 0);
    attn_mfma<<<dim3(512), dim3(256), 0, stream>>>(Zb, K2b, V2T, Ob, 2);
    gemmb(stream, 64, Ob, WT + wt_cao, WT + wt_cao, ca_bo, ca_bo, 1 << 30,
          Z, nullptr, Qb, nullptr, nullptr, 1, 4096, 512, 512, 1.f, 0, 0);

    sgemm4(stream, TEMB, tm_W1, tm_b1, TM1, SKP, 2048, 512, 1);
    sgemm4(stream, TM1, tm_W2, tm_b2, T4, SKP, 2048, 2048, 0);

    gemmb(stream, 64, Qb, WT + wt_in, WT + wt_in, in_b, in_b, 1 << 30,
          nullptr, H2, H2b, nullptr, nullptr, 1, 4096, 1024, 512, 1.f, 0, 0);
    for (int i = 0; i < 2; ++i) {
        sgemm4(stream, T4, film_W + (size_t)i * 4194304, film_b + i * 2048,
               FILM, SKP, 2048, 2048, 0);
        gemmb(stream, 64, H2b, WT + wt_res1 + (size_t)i * 2097152,
              WT + wt_res1 + (size_t)i * 2097152,
              res_b1 + i * 2048, res_b1 + i * 2048, 1 << 30,
              nullptr, nullptr, MIDb, nullptr, nullptr, 1, 4096, 2048, 1024, 1.f, 1, 0);
        gemmb(stream, 64, MIDb, WT + wt_res2 + (size_t)i * 2097152,
              WT + wt_res2 + (size_t)i * 2097152,
              res_b2 + i * 1024, res_b2 + i * 1024, 1 << 30,
              nullptr, Z2, nullptr, nullptr, nullptr, 1, 4096, 1024, 2048, 1.f, 0, 0);
        ln_kernel<<<4096, 256, 0, stream>>>(H2, Z2, rls + i * 1024, rlb + i * 1024,
                                            H2, H2b, 1024, FILM, 1024, 0);
    }

    gemmb(stream, 64, H2b, WT + wt_out, WT + wt_out, out_b, out_b, 1 << 30,
          nullptr, out, nullptr, nullptr, nullptr, 1, 4096, 256, 1024, 1.f, 0, 0);
}

// Round 18
// 1046.187 us; speedup vs baseline: 1.0344x; 1.0344x over previous
//
#include <hip/hip_runtime.h>
#include <hip/hip_bf16.h>

// ---------------------------------------------------------------------------
// B=4, L=1024, E=512, H=8, NL=2, M=2048, S=256, R=2, Dh=64
// Merged residual stream HB: 8192 rows, row = d*4096 + b*1024 + i.
// ---------------------------------------------------------------------------

#define NEGF -3.4028235e38f
#define LOG2E 1.4426950408889634f

using bf16x8 = __attribute__((ext_vector_type(8))) short;
using f32x4  = __attribute__((ext_vector_type(4))) float;

__device__ inline float bf2f(unsigned short u) {
    return __uint_as_float(((unsigned int)u) << 16);
}
__device__ inline unsigned short f2b(float f) {
    unsigned int u = __float_as_uint(f);
    return (unsigned short)((u + 0x7fff + ((u >> 16) & 1)) >> 16);
}

__device__ inline void gl_lds16(const void* g, void* l) {
    __builtin_amdgcn_global_load_lds(
        (const __attribute__((address_space(1))) void*)(uintptr_t)g,
        (__attribute__((address_space(3))) void*)(unsigned int)(uintptr_t)l,
        16, 0, 0);
}

// ---------------------------------------------------------------------------
// bf16 MFMA GEMM (R15 best config): BM in {64,128}, BN=128, BK=32, 4 waves,
// THREE LDS buffers, depth-2 prefetch, single top-of-iteration barrier,
// counted vmcnt (6/3/0 BM=64; 8/4/0 BM=128). XCD-chunked block swizzle.
// qkv==1 (N=1536): cols 0-511 -> Cb (Q, x0.125), 512-1023 -> CbK (K),
// 1024-1535 -> Ct (V per-head transposed (BB,8,64,1024)).
// qkv==0: Cf f32, Cb bf16, Ct per-head transposed with row-stride ldkv.
// ---------------------------------------------------------------------------
template<int BM>
__global__ __launch_bounds__(256) void gemm_bf16_k(
    const unsigned short* __restrict__ A,
    const unsigned short* __restrict__ Wt0, const unsigned short* __restrict__ Wt1,
    const float* __restrict__ bias0, const float* __restrict__ bias1, int mhalf,
    const float* __restrict__ res,
    float* __restrict__ Cf, unsigned short* __restrict__ Cb,
    unsigned short* __restrict__ CbK, unsigned short* __restrict__ Ct, int ldkv,
    int M, int N, int K, float alpha, int gelu_flag, int qkv)
{
    constexpr int MF  = BM / 32;
    constexpr int NAC = BM * 4 / 256;
    __shared__ unsigned short As[3][BM * 32];
    __shared__ unsigned short Bs[3][4096];
    const int tid  = threadIdx.x;
    const int wid  = tid >> 6;
    const int lane = tid & 63;
    const int wy   = wid >> 1, wx = wid & 1;
    const int koff = lane >> 4, l16 = lane & 15;

    const int flat = blockIdx.y * gridDim.x + blockIdx.x;
    const int cpx  = (gridDim.x * gridDim.y) >> 3;
    const int swz  = (flat & 7) * cpx + (flat >> 3);
    const int m0 = (swz / gridDim.x) * BM, n0 = (swz % gridDim.x) * 128;

    const unsigned short* Wt = (m0 < mhalf) ? Wt0 : Wt1;
    const float* bias = (m0 < mhalf) ? bias0 : bias1;

    const unsigned short* aG[NAC];
    const unsigned short* bG[2];
    #pragma unroll
    for (int i = 0; i < NAC; ++i) {
        int c = tid + i * 256;
        int r = ((c >> 6) << 4) | (c & 15), kk = ((c >> 4) & 3) << 3;
        aG[i] = A + (size_t)(m0 + r) * K + kk;
    }
    #pragma unroll
    for (int i = 0; i < 2; ++i) {
        int c = tid + i * 256;
        int r = ((c >> 6) << 4) | (c & 15), kk = ((c >> 4) & 3) << 3;
        bG[i] = Wt + (size_t)(n0 + r) * K + kk;
    }

    f32x4 acc[MF][4] = {};
    const int nk = K >> 5;

    auto stage = [&](int buf, int k0) {
        #pragma unroll
        for (int i = 0; i < NAC; ++i)
            gl_lds16(aG[i] + k0, &As[buf][(size_t)(i * 256 + wid * 64) * 8]);
        #pragma unroll
        for (int i = 0; i < 2; ++i)
            gl_lds16(bG[i] + k0, &Bs[buf][(size_t)(i * 256 + wid * 64) * 8]);
    };

    stage(0, 0);
    if (nk > 1) stage(1, 32);
    int cur = 0, nxt = 2;
    for (int it = 0; it < nk; ++it) {
        const int ahead = nk - 1 - it;
        if (ahead >= 2) stage(nxt, (it + 2) << 5);
        if constexpr (BM == 128) {
            if (ahead >= 2)      asm volatile("s_waitcnt vmcnt(8)" ::: "memory");
            else if (ahead == 1) asm volatile("s_waitcnt vmcnt(4)" ::: "memory");
            else                 asm volatile("s_waitcnt vmcnt(0)" ::: "memory");
        } else {
            if (ahead >= 2)      asm volatile("s_waitcnt vmcnt(6)" ::: "memory");
            else if (ahead == 1) asm volatile("s_waitcnt vmcnt(3)" ::: "memory");
            else                 asm volatile("s_waitcnt vmcnt(0)" ::: "memory");
        }
        __builtin_amdgcn_s_barrier();   // single rendezvous per K-step

        bf16x8 af[MF], bfr[4];
        const int foff = (koff * 16 + l16) * 8;
        #pragma unroll
        for (int i = 0; i < MF; ++i)
            af[i] = *(const bf16x8*)&As[cur][(size_t)((wy * MF + i) * 64) * 8 + foff];
        #pragma unroll
        for (int j = 0; j < 4; ++j)
            bfr[j] = *(const bf16x8*)&Bs[cur][(size_t)((wx * 4 + j) * 64) * 8 + foff];
        #pragma unroll
        for (int i = 0; i < MF; ++i)
            #pragma unroll
            for (int j = 0; j < 4; ++j)
                acc[i][j] = __builtin_amdgcn_mfma_f32_16x16x32_bf16(
                    af[i], bfr[j], acc[i][j], 0, 0, 0);

        cur = (cur == 2) ? 0 : cur + 1;
        nxt = (nxt == 2) ? 0 : nxt + 1;
    }

    #pragma unroll
    for (int i = 0; i < MF; ++i) {
        const int rbase = m0 + wy * (MF * 16) + i * 16 + koff * 4;
        #pragma unroll
        for (int j = 0; j < 4; ++j) {
            const int gn = n0 + wx * 64 + j * 16 + l16;
            const float bs = bias ? bias[gn] : 0.f;
            if (qkv) {
                const int seg = gn >> 9, gnl = gn & 511;
                const float av = (seg == 0) ? 0.125f : 1.0f;
                unsigned short o[4];
                #pragma unroll
                for (int r = 0; r < 4; ++r) o[r] = f2b((acc[i][j][r] + bs) * av);
                if (seg == 0) {
                    #pragma unroll
                    for (int r = 0; r < 4; ++r)
                        Cb[(size_t)(rbase + r) * 512 + gnl] = o[r];
                } else if (seg == 1) {
                    #pragma unroll
                    for (int r = 0; r < 4; ++r)
                        CbK[(size_t)(rbase + r) * 512 + gnl] = o[r];
                } else {
                    const int hh = gnl >> 6, dh = gnl & 63;
                    const int bb = rbase >> 10, l0 = rbase & 1023;
                    *(ushort4*)(Ct + ((size_t)(bb * 8 + hh) * 64 + dh) * 1024 + l0) =
                        make_ushort4(o[0], o[1], o[2], o[3]);
                }
            } else {
                float vr[4];
                #pragma unroll
                for (int r = 0; r < 4; ++r) {
                    float v = (acc[i][j][r] + bs) * alpha;
                    if (gelu_flag) v = 0.5f * v * (1.0f + erff(v * 0.70710678118654752f));
                    const size_t idx = (size_t)(rbase + r) * N + gn;
                    if (res) v += res[idx];
                    if (Cf) Cf[idx] = v;
                    if (Cb) Cb[idx] = f2b(v);
                    vr[r] = v;
                }
                if (Ct) {
                    const int hh = gn >> 6, dh = gn & 63;
                    const int bb = rbase / ldkv;
                    const int l0 = rbase - bb * ldkv;
                    *(ushort4*)(Ct + ((size_t)(bb * 8 + hh) * 64 + dh) * ldkv + l0) =
                        make_ushort4(f2b(vr[0]), f2b(vr[1]), f2b(vr[2]), f2b(vr[3]));
                }
            }
        }
    }
}

// ---------------------------------------------------------------------------
// weight transpose-convert: src fp32 [K][N] -> dst bf16 [N][K]
// ---------------------------------------------------------------------------
__global__ __launch_bounds__(256) void wconv(
    const float* __restrict__ src, unsigned short* __restrict__ dst,
    int K, int N, long sstride, long dstride)
{
    __shared__ float t[64][65];
    const int n0 = blockIdx.x * 64, k0 = blockIdx.y * 64;
    const float* s = src + (size_t)blockIdx.z * sstride;
    unsigned short* d = dst + (size_t)blockIdx.z * dstride;
    const int tid = threadIdx.x;
    #pragma unroll
    for (int i = 0; i < 4; ++i) {
        int lin = i * 1024 + tid * 4;
        int r = lin >> 6, c = lin & 63;
        float4 v = *(const float4*)(s + (size_t)(k0 + r) * N + n0 + c);
        t[r][c] = v.x; t[r][c + 1] = v.y; t[r][c + 2] = v.z; t[r][c + 3] = v.w;
    }
    __syncthreads();
    #pragma unroll
    for (int i = 0; i < 8; ++i) {
        int lin = i * 512 + tid * 2;
        int rn = lin >> 6, ck = lin & 63;
        ushort2 o;
        o.x = f2b(t[ck][rn]); o.y = f2b(t[ck + 1][rn]);
        *(ushort2*)(d + (size_t)(n0 + rn) * K + k0 + ck) = o;
    }
}

// ---------------------------------------------------------------------------
// Skinny GEMM for M=4, split-K, deterministic
// ---------------------------------------------------------------------------
__global__ __launch_bounds__(256) void skinny_k(
    const float* __restrict__ A, const float* __restrict__ W,
    float* __restrict__ P, int N, int K)
{
    const int n = blockIdx.x * 256 + threadIdx.x;
    const int s = blockIdx.y;
    const int k0 = s * 32;
    float a0 = 0.f, a1 = 0.f, a2 = 0.f, a3 = 0.f;
    #pragma unroll 8
    for (int k = k0; k < k0 + 32; ++k) {
        float w = W[(size_t)k * N + n];
        a0 = fmaf(A[k], w, a0);
        a1 = fmaf(A[K + k], w, a1);
        a2 = fmaf(A[2 * K + k], w, a2);
        a3 = fmaf(A[3 * K + k], w, a3);
    }
    float* p = P + (size_t)s * 4 * N;
    p[n] = a0; p[N + n] = a1; p[2 * N + n] = a2; p[3 * N + n] = a3;
}

__global__ __launch_bounds__(256) void skinny_red(
    const float* __restrict__ P, const float* __restrict__ bias,
    float* __restrict__ C, int N, int nsplit, int gelu_flag)
{
    const int n = blockIdx.x * 256 + threadIdx.x;
    const int r = blockIdx.y;
    float acc = 0.f;
    for (int s = 0; s < nsplit; ++s) acc += P[((size_t)s * 4 + r) * N + n];
    float v = acc + (bias ? bias[n] : 0.f);
    if (gelu_flag) v = 0.5f * v * (1.0f + erff(v * 0.70710678118654752f));
    C[(size_t)r * N + n] = v;
}

// ---------------------------------------------------------------------------
// LayerNorm (float2-vectorized); per-4096-row param offset pstride, optional
// add + FiLM; fp32 in, fp32 and/or bf16 out.
// ---------------------------------------------------------------------------
__global__ __launch_bounds__(256) void ln_kernel(
    const float* __restrict__ X, const float* __restrict__ X2,
    const float* __restrict__ s, const float* __restrict__ b,
    float* __restrict__ Yf, unsigned short* __restrict__ Yb,
    int D, const float* __restrict__ film, int rows_per_batch, long pstride)
{
    const int row = blockIdx.x;
    const int tid = threadIdx.x;
    const float* x = X + (size_t)row * D;
    const float* x2 = X2 ? X2 + (size_t)row * D : nullptr;
    const float* se = s + (size_t)(row >> 12) * pstride;
    const float* be = b + (size_t)(row >> 12) * pstride;

    float sum = 0.f, sq = 0.f;
    for (int c = tid * 2; c < D; c += 512) {
        float2 v2 = *(const float2*)(x + c);
        if (x2) { float2 w2 = *(const float2*)(x2 + c); v2.x += w2.x; v2.y += w2.y; }
        sum += v2.x + v2.y;
        sq  += v2.x * v2.x + v2.y * v2.y;
    }
    __shared__ float r1[4], r2[4];
    __shared__ float s_mean, s_rstd;
    for (int off = 32; off > 0; off >>= 1) {
        sum += __shfl_down(sum, off);
        sq  += __shfl_down(sq,  off);
    }
    if ((tid & 63) == 0) { r1[tid >> 6] = sum; r2[tid >> 6] = sq; }
    __syncthreads();
    if (tid == 0) {
        float ts = r1[0] + r1[1] + r1[2] + r1[3];
        float tq = r2[0] + r2[1] + r2[2] + r2[3];
        float mean = ts / (float)D;
        float var = tq / (float)D - mean * mean;
        s_mean = mean;
        s_rstd = rsqrtf(var + 1e-5f);
    }
    __syncthreads();
    const float mean = s_mean, rstd = s_rstd;
    const float* fa = nullptr; const float* fb = nullptr;
    if (film) {
        int batch = row / rows_per_batch;
        fa = film + (size_t)batch * 2 * D;
        fb = fa + D;
    }
    for (int c = tid * 2; c < D; c += 512) {
        float2 v2 = *(const float2*)(x + c);
        if (x2) { float2 w2 = *(const float2*)(x2 + c); v2.x += w2.x; v2.y += w2.y; }
        float y0 = (v2.x - mean) * rstd * se[c] + be[c];
        float y1 = (v2.y - mean) * rstd * se[c + 1] + be[c + 1];
        if (film) { y0 = fa[c] * y0 + fb[c]; y1 = fa[c + 1] * y1 + fb[c + 1]; }
        if (Yf) *(float2*)(Yf + (size_t)row * D + c) = make_float2(y0, y1);
        if (Yb) *(ushort2*)(Yb + (size_t)row * D + c) = make_ushort2(f2b(y0), f2b(y1));
    }
}

// ---------------------------------------------------------------------------
// Fused readout prologue (replaces add, 2x LN, add_bf16, build_allv):
// rows 0..4095: read L2R/R2L row; Z = sum (fp32); n1 = LN1(L2R), n2 = LN2(R2L)
//   -> bf16 into ALLV rows (b*2080+1+i) and (b*2080+1025+i); n1+n2 -> SUM.
// rows 4096..4099: copy temb bf16 row into ALLV row b*2080.
// ---------------------------------------------------------------------------
__global__ __launch_bounds__(256) void readout_fuse(
    const float* __restrict__ L2R, const float* __restrict__ R2L,
    const float* __restrict__ s1, const float* __restrict__ b1,
    const float* __restrict__ s2, const float* __restrict__ b2,
    const unsigned short* __restrict__ tembb,
    float* __restrict__ Z, unsigned short* __restrict__ allv,
    unsigned short* __restrict__ SUM)
{
    const int row = blockIdx.x;
    const int tid = threadIdx.x;
    if (row >= 4096) {
        const int b = row - 4096;
        if (tid < 64)
            ((uint4*)(allv + (size_t)b * 2080 * 512))[tid] =
                ((const uint4*)(tembb + b * 512))[tid];
        return;
    }
    const int b = row >> 10, i = row & 1023;
    const float* x1 = L2R + (size_t)row * 512;
    const float* x2 = R2L + (size_t)row * 512;
    const int c = tid * 2;
    float2 a1 = *(const float2*)(x1 + c);
    float2 a2 = *(const float2*)(x2 + c);

    float su1 = a1.x + a1.y, sk1 = a1.x * a1.x + a1.y * a1.y;
    float su2 = a2.x + a2.y, sk2 = a2.x * a2.x + a2.y * a2.y;
    __shared__ float rr[4][4];
    __shared__ float st[4];
    for (int off = 32; off > 0; off >>= 1) {
        su1 += __shfl_down(su1, off);
        sk1 += __shfl_down(sk1, off);
        su2 += __shfl_down(su2, off);
        sk2 += __shfl_down(sk2, off);
    }
    if ((tid & 63) == 0) {
        rr[tid >> 6][0] = su1; rr[tid >> 6][1] = sk1;
        rr[tid >> 6][2] = su2; rr[tid >> 6][3] = sk2;
    }
    __syncthreads();
    if (tid == 0) {
        float t0 = rr[0][0] + rr[1][0] + rr[2][0] + rr[3][0];
        float t1 = rr[0][1] + rr[1][1] + rr[2][1] + rr[3][1];
        float t2 = rr[0][2] + rr[1][2] + rr[2][2] + rr[3][2];
        float t3 = rr[0][3] + rr[1][3] + rr[2][3] + rr[3][3];
        float m1 = t0 / 512.f, m2 = t2 / 512.f;
        st[0] = m1;
        st[1] = rsqrtf(t1 / 512.f - m1 * m1 + 1e-5f);
        st[2] = m2;
        st[3] = rsqrtf(t3 / 512.f - m2 * m2 + 1e-5f);
    }
    __syncthreads();
    const float m1 = st[0], r1v = st[1], m2 = st[2], r2v = st[3];

    // Z = sum (fp32)
    *(float2*)(Z + (size_t)row * 512 + c) = make_float2(a1.x + a2.x, a1.y + a2.y);

    float n1x = (a1.x - m1) * r1v * s1[c]     + b1[c];
    float n1y = (a1.y - m1) * r1v * s1[c + 1] + b1[c + 1];
    float n2x = (a2.x - m2) * r2v * s2[c]     + b2[c];
    float n2y = (a2.y - m2) * r2v * s2[c + 1] + b2[c + 1];

    unsigned short* l2rn = allv + ((size_t)(b * 2080 + 1 + i)) * 512;
    unsigned short* r2ln = allv + ((size_t)(b * 2080 + 1025 + i)) * 512;
    *(ushort2*)(l2rn + c) = make_ushort2(f2b(n1x), f2b(n1y));
    *(ushort2*)(r2ln + c) = make_ushort2(f2b(n2x), f2b(n2y));
    *(ushort2*)(SUM + (size_t)row * 512 + c) =
        make_ushort2(f2b(n1x + n2x), f2b(n1y + n2y));
}

__global__ void temb_kernel(const float* __restrict__ t, float* __restrict__ temb,
                            unsigned short* __restrict__ tembb)
{
    int b = blockIdx.x;
    int i = threadIdx.x;
    float f = expf((float)i * (-9.210340371976184f / 255.0f));
    float a = t[b] * f;
    float sv = sinf(a), cv = cosf(a);
    temb[b * 512 + i]        = sv;
    temb[b * 512 + 256 + i]  = cv;
    tembb[b * 512 + i]       = f2b(sv);
    tembb[b * 512 + 256 + i] = f2b(cv);
}

__global__ void embed_kernel(const int* __restrict__ x, const float* __restrict__ temb,
                             const float* __restrict__ embed,
                             float* __restrict__ l2r, float* __restrict__ r2l)
{
    const int i = blockIdx.x;
    const int b = blockIdx.y;
    const int d = blockIdx.z;
    float* out = (d == 0 ? l2r : r2l) + ((size_t)(b * 1024 + i) * 512);
    const float* src;
    if (d == 0) src = (i == 0)    ? temb + b * 512 : embed + (size_t)x[b * 1024 + (i - 1)] * 512;
    else        src = (i == 1023) ? temb + b * 512 : embed + (size_t)x[b * 1024 + (i + 1)] * 512;
    for (int e = threadIdx.x; e < 512; e += 256) {
        int j = e >> 1;
        float div = expf((float)(2 * j) * (-9.210340371976184f / 512.0f));
        float ang = (float)i * div;
        float pe = (e & 1) ? cosf(ang) : sinf(ang);
        out[e] = src[e] + pe;
    }
}

// ---------------------------------------------------------------------------
// MFMA flash attention (R15 best variant: KVBLK=64), bf16 in/out, fp32
// accumulate, T14 async staging with named uint4 registers. Equal-work
// pairing for merged self-attention: block does (qt, 15-qt) sequentially
// -> exactly 17 tiles per block.
// mode -1 (merged self): grid 512; qp=w&7, h=(w>>3)&7, bb=w>>6, dir=bb>>2.
// mode  2 (cross):       grid 512; qt=w&15, h=(w>>4)&7, bb=w>>7.
// ---------------------------------------------------------------------------
__global__ __launch_bounds__(256) void attn_mfma(
    const unsigned short* __restrict__ Q, const unsigned short* __restrict__ K,
    const unsigned short* __restrict__ Vt, unsigned short* __restrict__ O, int mode)
{
    const int E = 512;
    const int LKP = (mode == 2) ? 2080 : 1024;
    const int idf = blockIdx.x;
    const int chunk = gridDim.x >> 3;
    const int w = (idf & 7) * chunk + (idf >> 3);
    int h, bb, dir, qn, qtA;
    if (mode == 2) { qn = 1; qtA = w & 15; h = (w >> 4) & 7; bb = w >> 7; dir = 2; }
    else           { qn = 2; qtA = w & 7;  h = (w >> 3) & 7; bb = w >> 6; dir = bb >> 2; }
    const int tid = threadIdx.x;
    const int wid = tid >> 6, lane = tid & 63;
    const int fr = lane & 15;
    const int fs = lane >> 4;

    __shared__ unsigned short Qs[4096];
    __shared__ unsigned short Ks[4096];
    __shared__ unsigned short Vs[4096];
    __shared__ unsigned short Ps[4][16][72];

    const unsigned short* Kb0 = K + ((size_t)bb * LKP) * E + h * 64;
    const unsigned short* Vb0 = Vt + (size_t)(bb * 8 + h) * 64 * LKP;
    const int sr = tid & 63, sc = tid >> 6;

    uint4 kr0, kr1, vr0, vr1;
#define LOAD_TILE(KT) do {                                                     \
        const unsigned short* Kbase_ = Kb0 + (size_t)((KT) * 64) * E;          \
        const unsigned short* Vbase_ = Vb0 + (KT) * 64;                        \
        kr0 = *(const uint4*)(Kbase_ + (size_t)sr * E + sc * 8);               \
        kr1 = *(const uint4*)(Kbase_ + (size_t)sr * E + (sc + 4) * 8);         \
        vr0 = *(const uint4*)(Vbase_ + (size_t)sr * LKP + sc * 8);             \
        vr1 = *(const uint4*)(Vbase_ + (size_t)sr * LKP + (sc + 4) * 8);       \
    } while (0)

    for (int p = 0; p < qn; ++p) {
        const int qt = (p == 0) ? qtA : (15 - qtA);
        const int q0 = qt * 64;
        const int wq0 = q0 + wid * 16;

        {
            const unsigned short* Qbase = Q + ((size_t)bb * 1024 + q0) * E + h * 64;
            #pragma unroll
            for (int it = 0; it < 2; ++it) {
                int i = tid + it * 256;
                int r = i & 63, c = i >> 6;
                *(uint4*)&Qs[(size_t)(c * 64 + r) * 8] =
                    *(const uint4*)(Qbase + (size_t)r * E + c * 8);
            }
        }
        __syncthreads();
        const bf16x8 aq0 = *(const bf16x8*)&Qs[(size_t)(fs * 64 + wid * 16 + fr) * 8];
        const bf16x8 aq1 = *(const bf16x8*)&Qs[(size_t)((fs + 4) * 64 + wid * 16 + fr) * 8];

        float m_r[4], l_r[4];
        f32x4 o_acc[4] = {};
        #pragma unroll
        for (int r = 0; r < 4; ++r) { m_r[r] = NEGF; l_r[r] = 0.f; }

        int nt, ktA = 1;
        if (dir == 0)      nt = qt + 1;
        else if (dir == 1) nt = 16 - qt;
        else { ktA = (qt >= 1) ? qt : 1; nt = 1 + (qt + 16 - ktA + 1); }
        auto kt_of = [&](int j) -> int {
            if (dir == 0) return j;
            if (dir == 1) return qt + j;
            return (j == 0) ? 0 : (ktA + j - 1);
        };

        LOAD_TILE(kt_of(0));

        for (int j = 0; j < nt; ++j) {
            const int kt = kt_of(j);
            const int k0 = kt * 64;

            asm volatile("s_waitcnt lgkmcnt(0)" ::: "memory");
            __builtin_amdgcn_s_barrier();

            *(uint4*)&Ks[(size_t)(sc * 64 + sr) * 8]       = kr0;
            *(uint4*)&Ks[(size_t)((sc + 4) * 64 + sr) * 8] = kr1;
            *(uint4*)&Vs[(size_t)(sc * 64 + sr) * 8]       = vr0;
            *(uint4*)&Vs[(size_t)((sc + 4) * 64 + sr) * 8] = vr1;
            if (j + 1 < nt) LOAD_TILE(kt_of(j + 1));
            else if (p + 1 < qn) {
                const int qt2 = 15 - qtA;
                const int kt2 = (dir == 0) ? 0 : ((dir == 1) ? qt2 : 0);
                LOAD_TILE(kt2);
            }

            asm volatile("s_waitcnt lgkmcnt(0)" ::: "memory");
            __builtin_amdgcn_s_barrier();

            f32x4 s[4] = {};
            __builtin_amdgcn_s_setprio(1);
            #pragma unroll
            for (int t = 0; t < 4; ++t) {
                bf16x8 bk0 = *(const bf16x8*)&Ks[(size_t)(fs * 64 + t * 16 + fr) * 8];
                bf16x8 bk1 = *(const bf16x8*)&Ks[(size_t)((fs + 4) * 64 + t * 16 + fr) * 8];
                s[t] = __builtin_amdgcn_mfma_f32_16x16x32_bf16(aq0, bk0, s[t], 0, 0, 0);
                s[t] = __builtin_amdgcn_mfma_f32_16x16x32_bf16(aq1, bk1, s[t], 0, 0, 0);
            }
            __builtin_amdgcn_s_setprio(0);

            bool need_mask;
            if (dir != 2) need_mask = (kt == qt);
            else if (kt >= 1 && kt <= 15) need_mask = !((64 * kt - 1) > (q0 + 63));
            else if (kt >= 17)            need_mask = !((64 * kt + 63 - 1025) < q0);
            else                          need_mask = true;
            if (need_mask) {
                #pragma unroll
                for (int t = 0; t < 4; ++t) {
                    #pragma unroll
                    for (int r = 0; r < 4; ++r) {
                        int q = wq0 + fs * 4 + r;
                        int k = k0 + t * 16 + fr;
                        bool valid;
                        if (dir == 0)      valid = (k <= q);
                        else if (dir == 1) valid = (k >= q);
                        else valid = (k == 0) || (k <= 1024 ? (k - 1) > q : (k - 1025) < q);
                        if (!valid) s[t][r] = NEGF;
                    }
                }
            }

            float c_[4], rs[4];
            #pragma unroll
            for (int r = 0; r < 4; ++r) {
                float v = fmaxf(fmaxf(s[0][r], s[1][r]), fmaxf(s[2][r], s[3][r]));
                v = fmaxf(v, __shfl_xor(v, 1));
                v = fmaxf(v, __shfl_xor(v, 2));
                v = fmaxf(v, __shfl_xor(v, 4));
                v = fmaxf(v, __shfl_xor(v, 8));
                float mnew = fmaxf(m_r[r], v);
                c_[r] = exp2f((m_r[r] - mnew) * LOG2E);
                m_r[r] = mnew;
                rs[r] = 0.f;
            }
            #pragma unroll
            for (int t = 0; t < 4; ++t) {
                #pragma unroll
                for (int r = 0; r < 4; ++r) {
                    float pv = exp2f((s[t][r] - m_r[r]) * LOG2E);
                    s[t][r] = pv;
                    rs[r] += pv;
                }
            }
            #pragma unroll
            for (int r = 0; r < 4; ++r) {
                float v = rs[r];
                v += __shfl_xor(v, 1);
                v += __shfl_xor(v, 2);
                v += __shfl_xor(v, 4);
                v += __shfl_xor(v, 8);
                l_r[r] = l_r[r] * c_[r] + v;
                o_acc[0][r] *= c_[r]; o_acc[1][r] *= c_[r];
                o_acc[2][r] *= c_[r]; o_acc[3][r] *= c_[r];
            }

            #pragma unroll
            for (int t = 0; t < 4; ++t)
                #pragma unroll
                for (int r = 0; r < 4; ++r)
                    Ps[wid][fs * 4 + r][t * 16 + fr] = f2b(s[t][r]);

            bf16x8 pa0 = *(const bf16x8*)&Ps[wid][fr][fs * 8];
            bf16x8 pa1 = *(const bf16x8*)&Ps[wid][fr][fs * 8 + 32];
            __builtin_amdgcn_s_setprio(1);
            #pragma unroll
            for (int t = 0; t < 4; ++t) {
                bf16x8 bv0 = *(const bf16x8*)&Vs[(size_t)(fs * 64 + t * 16 + fr) * 8];
                bf16x8 bv1 = *(const bf16x8*)&Vs[(size_t)((fs + 4) * 64 + t * 16 + fr) * 8];
                o_acc[t] = __builtin_amdgcn_mfma_f32_16x16x32_bf16(pa0, bv0, o_acc[t], 0, 0, 0);
                o_acc[t] = __builtin_amdgcn_mfma_f32_16x16x32_bf16(pa1, bv1, o_acc[t], 0, 0, 0);
            }
            __builtin_amdgcn_s_setprio(0);
        }

        unsigned short* Obase = O + ((size_t)bb * 1024 + q0) * E + h * 64;
        float invl[4];
        #pragma unroll
        for (int r = 0; r < 4; ++r) invl[r] = 1.f / l_r[r];
        #pragma unroll
        for (int t = 0; t < 4; ++t)
            #pragma unroll
            for (int r = 0; r < 4; ++r)
                Obase[(size_t)(wid * 16 + fs * 4 + r) * E + t * 16 + fr] =
                    f2b(o_acc[t][r] * invl[r]);

        if (p + 1 < qn) __syncthreads();
    }
#undef LOAD_TILE
}

// ---------------------------------------------------------------------------

static inline void gemmb(hipStream_t st, int BM, const unsigned short* A,
                         const unsigned short* Wt0, const unsigned short* Wt1,
                         const float* bias0, const float* bias1, int mhalf,
                         const float* res, float* Cf, unsigned short* Cb,
                         unsigned short* CbK, unsigned short* Ct, int ldkv,
                         int M, int N, int K, float alpha, int gelu, int qkv)
{
    dim3 g(N / 128, M / BM);
    if (BM == 128)
        gemm_bf16_k<128><<<g, dim3(256), 0, st>>>(A, Wt0, Wt1, bias0, bias1, mhalf,
            res, Cf, Cb, CbK, Ct, ldkv, M, N, K, alpha, gelu, qkv);
    else
        gemm_bf16_k<64><<<g, dim3(256), 0, st>>>(A, Wt0, Wt1, bias0, bias1, mhalf,
            res, Cf, Cb, CbK, Ct, ldkv, M, N, K, alpha, gelu, qkv);
}

static inline void sgemm4(hipStream_t st, const float* A, const float* W,
                          const float* bias, float* C, float* P,
                          int N, int K, int gelu)
{
    const int nsplit = K / 32;
    skinny_k<<<dim3(N / 256, nsplit), 256, 0, st>>>(A, W, P, N, K);
    skinny_red<<<dim3(N / 256, 4), 256, 0, st>>>(P, bias, C, N, nsplit, gelu);
}

extern "C" void kernel_launch(void* const* d_in, const int* in_sizes, int n_in,
                              void* d_out, int out_size, void* d_ws, size_t ws_size,
                              hipStream_t stream)
{
    const int*   x      = (const int*)  d_in[0];
    const float* t      = (const float*)d_in[1];
    const float* embedW = (const float*)d_in[2];
    const float* attn_W = (const float*)d_in[3];
    const float* attn_b = (const float*)d_in[4];
    const float* ln_s   = (const float*)d_in[5];
    const float* ln_b   = (const float*)d_in[6];
    const float* mlp_W1 = (const float*)d_in[7];
    const float* mlp_b1 = (const float*)d_in[8];
    const float* mlp_W2 = (const float*)d_in[9];
    const float* mlp_b2 = (const float*)d_in[10];
    const float* ca_Wq  = (const float*)d_in[11];
    const float* ca_Wk  = (const float*)d_in[12];
    const float* ca_bk  = (const float*)d_in[13];
    const float* ca_Wv  = (const float*)d_in[14];
    const float* ca_bv  = (const float*)d_in[15];
    const float* ca_Wo  = (const float*)d_in[16];
    const float* ca_bo  = (const float*)d_in[17];
    const float* ro1s   = (const float*)d_in[18];
    const float* ro1b   = (const float*)d_in[19];
    const float* ro2s   = (const float*)d_in[20];
    const float* ro2b   = (const float*)d_in[21];
    const float* in_W   = (const float*)d_in[22];
    const float* in_b   = (const float*)d_in[23];
    const float* tm_W1  = (const float*)d_in[24];
    const float* tm_b1  = (const float*)d_in[25];
    const float* tm_W2  = (const float*)d_in[26];
    const float* tm_b2  = (const float*)d_in[27];
    const float* res_W1 = (const float*)d_in[28];
    const float* res_b1 = (const float*)d_in[29];
    const float* res_W2 = (const float*)d_in[30];
    const float* res_b2 = (const float*)d_in[31];
    const float* rls    = (const float*)d_in[32];
    const float* rlb    = (const float*)d_in[33];
    const float* film_W = (const float*)d_in[34];
    const float* film_b = (const float*)d_in[35];
    const float* out_W  = (const float*)d_in[36];
    const float* out_b  = (const float*)d_in[37];
    float* out = (float*)d_out;
    (void)ws_size; (void)in_sizes; (void)n_in; (void)out_size;

    char* base = (char*)d_ws;
    size_t off = 0;
    auto alloc = [&](size_t bytes) -> char* {
        char* p = base + off;
        off = (off + bytes + 255) & ~(size_t)255;
        return p;
    };
    float* TEMB  = (float*)alloc(8192);
    float* TM1   = (float*)alloc(32768);
    float* T4    = (float*)alloc(32768);
    float* FILM  = (float*)alloc(32768);
    unsigned short* TEMBb = (unsigned short*)alloc(4096);
    float* SKP   = (float*)alloc(2097152);

    float* HB  = (float*)alloc(16777216);        // merged residual stream (8192x512)
    float* L2R = HB;
    float* R2L = HB + 4096 * 512;
    float* Z   = (float*)alloc(8388608);
    float* H2  = (float*)alloc(16777216);
    float* Z2  = (float*)alloc(16777216);

    unsigned short* Zb  = (unsigned short*)alloc(8388608);   // 8192x512
    unsigned short* Qb  = (unsigned short*)alloc(8388608);
    unsigned short* Kb  = (unsigned short*)alloc(8388608);
    unsigned short* Vb  = (unsigned short*)alloc(8388608);   // V^T (8,8,64,1024)
    unsigned short* Ob  = (unsigned short*)alloc(8388608);
    unsigned short* H2b = (unsigned short*)alloc(8388608);

    unsigned short* BIG = (unsigned short*)alloc(33554432);
    unsigned short* MIDb  = BIG;                 // 8192x2048 bf16 (32 MB)
    unsigned short* ALLVb = BIG;                 // 8320x512 (readout)
    unsigned short* K2b   = BIG + 4259840;
    unsigned short* V2T   = BIG + 8519680;       // (4,8,64,2080)

    unsigned short* WT = (unsigned short*)alloc(45613056);
    const size_t wt_attn = 0,        wt_mlp1 = 4194304, wt_mlp2 = 8388608;
    const size_t wt_caq = 12582912,  wt_cak = 12845056, wt_cav = 13107200,
                 wt_cao = 13369344,  wt_in  = 13631488;
    const size_t wt_res1 = 14155776, wt_res2 = 18350080, wt_out = 22544384;

    wconv<<<dim3(8, 8, 16), 256, 0, stream>>>(attn_W, WT + wt_attn, 512, 512, 262144, 262144);
    wconv<<<dim3(32, 8, 4), 256, 0, stream>>>(mlp_W1, WT + wt_mlp1, 512, 2048, 1048576, 1048576);
    wconv<<<dim3(8, 32, 4), 256, 0, stream>>>(mlp_W2, WT + wt_mlp2, 2048, 512, 1048576, 1048576);
    wconv<<<dim3(8, 8), 256, 0, stream>>>(ca_Wq, WT + wt_caq, 512, 512, 0, 0);
    wconv<<<dim3(8, 8), 256, 0, stream>>>(ca_Wk, WT + wt_cak, 512, 512, 0, 0);
    wconv<<<dim3(8, 8), 256, 0, stream>>>(ca_Wv, WT + wt_cav, 512, 512, 0, 0);
    wconv<<<dim3(8, 8), 256, 0, stream>>>(ca_Wo, WT + wt_cao, 512, 512, 0, 0);
    wconv<<<dim3(16, 8), 256, 0, stream>>>(in_W, WT + wt_in, 512, 1024, 0, 0);
    wconv<<<dim3(32, 16, 2), 256, 0, stream>>>(res_W1, WT + wt_res1, 1024, 2048, 2097152, 2097152);
    wconv<<<dim3(16, 32, 2), 256, 0, stream>>>(res_W2, WT + wt_res2, 2048, 1024, 2097152, 2097152);
    wconv<<<dim3(4, 16), 256, 0, stream>>>(out_W, WT + wt_out, 1024, 256, 0, 0);

    temb_kernel<<<dim3(4), dim3(256), 0, stream>>>(t, TEMB, TEMBb);
    embed_kernel<<<dim3(1024, 4, 2), dim3(256), 0, stream>>>(x, TEMB, embedW, L2R, R2L);

    // ---- transformer blocks, both directions merged (M=8192) ----
    for (int l = 0; l < 2; ++l) {
        const size_t d1 = 2 + l;   // dl for d=1
        ln_kernel<<<8192, 256, 0, stream>>>(HB, nullptr,
            ln_s + (l * 2 + 0) * 512, ln_b + (l * 2 + 0) * 512,
            nullptr, Zb, 512, nullptr, 1024, 2048);
        gemmb(stream, 64, Zb,
              WT + wt_attn + (size_t)l * 1048576, WT + wt_attn + d1 * 1048576,
              attn_b + l * 2048, attn_b + d1 * 2048, 4096,
              nullptr, nullptr, Qb, Kb, Vb, 1024, 8192, 1536, 512, 1.f, 0, 1);
        attn_mfma<<<dim3(512), dim3(256), 0, stream>>>(Qb, Kb, Vb, Ob, -1);
        gemmb(stream, 64, Ob,
              WT + wt_attn + (size_t)(l * 4 + 3) * 262144,
              WT + wt_attn + (d1 * 4 + 3) * 262144,
              attn_b + (l * 4 + 3) * 512, attn_b + (d1 * 4 + 3) * 512, 4096,
              HB, HB, nullptr, nullptr, nullptr, 1, 8192, 512, 512, 1.f, 0, 0);
        ln_kernel<<<8192, 256, 0, stream>>>(HB, nullptr,
            ln_s + (l * 2 + 1) * 512, ln_b + (l * 2 + 1) * 512,
            nullptr, Zb, 512, nullptr, 1024, 2048);
        gemmb(stream, 64, Zb,
              WT + wt_mlp1 + (size_t)l * 1048576, WT + wt_mlp1 + d1 * 1048576,
              mlp_b1 + l * 2048, mlp_b1 + d1 * 2048, 4096,
              nullptr, nullptr, MIDb, nullptr, nullptr, 1, 8192, 2048, 512, 1.f, 1, 0);
        gemmb(stream, 64, MIDb,
              WT + wt_mlp2 + (size_t)l * 1048576, WT + wt_mlp2 + d1 * 1048576,
              mlp_b2 + l * 512, mlp_b2 + d1 * 512, 4096,
              HB, HB, nullptr, nullptr, nullptr, 1, 8192, 512, 2048, 1.f, 0, 0);
    }

    // ---- readout / cross-attention (M=4096) ----
    readout_fuse<<<dim3(4100), 256, 0, stream>>>(L2R, R2L, ro1s, ro1b, ro2s, ro2b,
                                                 TEMBb, Z, ALLVb, Vb);
    gemmb(stream, 64, Vb, WT + wt_caq, WT + wt_caq, nullptr, nullptr, 1 << 30,
          nullptr, nullptr, Zb, nullptr, nullptr, 1, 4096, 512, 512, 0.125f, 0, 0);
    gemmb(stream, 64, ALLVb, WT + wt_cak, WT + wt_cak, ca_bk, ca_bk, 1 << 30,
          nullptr, nullptr, K2b, nullptr, nullptr, 1, 8320, 512, 512, 1.f, 0, 0);
    gemmb(stream, 64, ALLVb, WT + wt_cav, WT + wt_cav, ca_bv, ca_bv, 1 << 30,
          nullptr, nullptr, nullptr, nullptr, V2T, 2080, 8320, 512, 512, 1.f, 0, 0);
    attn_mfma<<<dim3(512), dim3(256), 0, stream>>>(Zb, K2b, V2T, Ob, 2);
    gemmb(stream, 64, Ob, WT + wt_cao, WT + wt_cao, ca_bo, ca_bo, 1 << 30,
          Z, nullptr, Qb, nullptr, nullptr, 1, 4096, 512, 512, 1.f, 0, 0);

    sgemm4(stream, TEMB, tm_W1, tm_b1, TM1, SKP, 2048, 512, 1);
    sgemm4(stream, TM1, tm_W2, tm_b2, T4, SKP, 2048, 2048, 0);

    gemmb(stream, 64, Qb, WT + wt_in, WT + wt_in, in_b, in_b, 1 << 30,
          nullptr, H2, H2b, nullptr, nullptr, 1, 4096, 1024, 512, 1.f, 0, 0);
    for (int i = 0; i < 2; ++i) {
        sgemm4(stream, T4, film_W + (size_t)i * 4194304, film_b + i * 2048,
               FILM, SKP, 2048, 2048, 0);
        gemmb(stream, 64, H2b, WT + wt_res1 + (size_t)i * 2097152,
              WT + wt_res1 + (size_t)i * 2097152,
              res_b1 + i * 2048, res_b1 + i * 2048, 1 << 30,
              nullptr, nullptr, MIDb, nullptr, nullptr, 1, 4096, 2048, 1024, 1.f, 1, 0);
        gemmb(stream, 64, MIDb, WT + wt_res2 + (size_t)i * 2097152,
              WT + wt_res2 + (size_t)i * 2097152,
              res_b2 + i * 1024, res_b2 + i * 1024, 1 << 30,
              nullptr, Z2, nullptr, nullptr, nullptr, 1, 4096, 1024, 2048, 1.f, 0, 0);
        ln_kernel<<<4096, 256, 0, stream>>>(H2, Z2, rls + i * 1024, rlb + i * 1024,
                                            H2, H2b, 1024, FILM, 1024, 0);
    }

    gemmb(stream, 64, H2b, WT + wt_out, WT + wt_out, out_b, out_b, 1 << 30,
          nullptr, out, nullptr, nullptr, nullptr, 1, 4096, 256, 1024, 1.f, 0, 0);
}